// Round 1
// baseline (178087.598 us; speedup 1.0000x reference)
//
#include <hip/hip_runtime.h>

#define TT 8192
#define DD 2048
#define NWG 256
#define RPW (DD / NWG)   // 8 rows of h per workgroup
#define NTH 256

// ---------------- Phase 1: pre = x @ W1^T + b1  (M=TT, N=DD, K=DD) ----------
#define BM 128
#define BN 128
#define BK 16

__global__ __launch_bounds__(NTH)
void gemm_abt_bias(const float* __restrict__ A, const float* __restrict__ B,
                   const float* __restrict__ bias, float* __restrict__ C,
                   int M, int N, int K) {
  // C[m][n] = sum_k A[m][k] * B[n][k] + bias[n]; both operands K-contiguous.
  __shared__ float As[BK][BM + 4];   // +4 pad: keeps 16B alignment, breaks bank conflicts
  __shared__ float Bs[BK][BN + 4];
  const int ntile = N / BN;
  const int bn = blockIdx.x % ntile;
  const int bm = blockIdx.x / ntile;
  const int tid = (int)threadIdx.x;
  const int tx = tid & 15;
  const int ty = tid >> 4;

  float acc[8][8];
#pragma unroll
  for (int i = 0; i < 8; ++i)
#pragma unroll
    for (int j = 0; j < 8; ++j) acc[i][j] = 0.f;

  for (int kt = 0; kt < K; kt += BK) {
#pragma unroll
    for (int i = 0; i < 2; ++i) {
      int f = tid + i * 256;          // 512 float4s per tile
      int row = f >> 2, c4 = f & 3;
      const float4 av = *(const float4*)(A + (size_t)(bm * BM + row) * K + kt + c4 * 4);
      As[c4 * 4 + 0][row] = av.x; As[c4 * 4 + 1][row] = av.y;
      As[c4 * 4 + 2][row] = av.z; As[c4 * 4 + 3][row] = av.w;
      const float4 bv = *(const float4*)(B + (size_t)(bn * BN + row) * K + kt + c4 * 4);
      Bs[c4 * 4 + 0][row] = bv.x; Bs[c4 * 4 + 1][row] = bv.y;
      Bs[c4 * 4 + 2][row] = bv.z; Bs[c4 * 4 + 3][row] = bv.w;
    }
    __syncthreads();
#pragma unroll
    for (int kk = 0; kk < BK; ++kk) {
      float a[8], b[8];
      *(float4*)&a[0] = *(const float4*)&As[kk][ty * 8];
      *(float4*)&a[4] = *(const float4*)&As[kk][ty * 8 + 4];
      *(float4*)&b[0] = *(const float4*)&Bs[kk][tx * 8];
      *(float4*)&b[4] = *(const float4*)&Bs[kk][tx * 8 + 4];
#pragma unroll
      for (int i = 0; i < 8; ++i)
#pragma unroll
        for (int j = 0; j < 8; ++j) acc[i][j] += a[i] * b[j];
    }
    __syncthreads();
  }

  const int col0 = bn * BN + tx * 8;
  const float4 bv0 = *(const float4*)(bias + col0);
  const float4 bv1 = *(const float4*)(bias + col0 + 4);
#pragma unroll
  for (int i = 0; i < 8; ++i) {
    float* crow = C + (size_t)(bm * BM + ty * 8 + i) * N + col0;
    float4 v0 = { acc[i][0] + bv0.x, acc[i][1] + bv0.y, acc[i][2] + bv0.z, acc[i][3] + bv0.w };
    float4 v1 = { acc[i][4] + bv1.x, acc[i][5] + bv1.y, acc[i][6] + bv1.z, acc[i][7] + bv1.w };
    *(float4*)(crow) = v0;
    *(float4*)(crow + 4) = v1;
  }
}

// ---------------- Phase 2: persistent recurrent kernel ----------------------
__device__ __forceinline__ float wave_sum(float v) {
#pragma unroll
  for (int off = 32; off > 0; off >>= 1) v += __shfl_down(v, off, 64);
  return v;
}

__global__ void __launch_bounds__(NTH, 1)
recurrent_kernel(const float* __restrict__ h0,
                 const float* __restrict__ W2,
                 const float* __restrict__ b2,
                 const float* __restrict__ pre,
                 const float* __restrict__ Wf,
                 const float* __restrict__ bf,
                 float* __restrict__ out,
                 float* hbuf,      // 2*DD floats, double-buffered h
                 int*   done) {    // NWG flags, zeroed before launch
  __shared__ float w2s[RPW][DD];   // 64 KB: this WG's 8 rows of W2, pinned all steps
  __shared__ float hs[DD];         // 8 KB: current h
  __shared__ float pres[RPW];

  const int wg   = (int)blockIdx.x;
  const int tid  = (int)threadIdx.x;
  const int lane = tid & 63;
  const int wave = tid >> 6;           // 4 waves; wave handles local rows 2w, 2w+1
  const int r0 = 2 * wave, r1 = 2 * wave + 1;

  // Pin W2 rows [wg*8, wg*8+8) in LDS.
  {
    const float4* src = (const float4*)(W2 + (size_t)wg * RPW * DD);
    float4* dst = (float4*)&w2s[0][0];
    for (int i = tid; i < RPW * DD / 4; i += NTH) dst[i] = src[i];
  }
  const float b2r0 = b2[wg * RPW + r0];
  const float b2r1 = b2[wg * RPW + r1];
  __syncthreads();

  for (int t = 0; t < TT; ++t) {
    // pre[t] rows for this WG: no dependency on the barrier -> issue early.
    float myPre = 0.f;
    if (tid < RPW) myPre = pre[(size_t)t * DD + wg * RPW + tid];

    if (t == 0) {
      // h_0 straight from the input; no sync needed.
      ((float4*)hs)[2 * tid]     = ((const float4*)h0)[2 * tid];
      ((float4*)hs)[2 * tid + 1] = ((const float4*)h0)[2 * tid + 1];
    } else {
      // Thread j waits for chunk j (8 floats) of h_t, then stages exactly it.
      // Acquire load -> buffer_inv -> following normal loads read fresh LLC data.
      while (__hip_atomic_load(&done[tid], __ATOMIC_ACQUIRE,
                               __HIP_MEMORY_SCOPE_AGENT) < t) {
        __builtin_amdgcn_s_sleep(2);
      }
      const float4* hb4 = (const float4*)(hbuf + (size_t)(t & 1) * DD);
      ((float4*)hs)[2 * tid]     = hb4[2 * tid];
      ((float4*)hs)[2 * tid + 1] = hb4[2 * tid + 1];
    }
    if (tid < RPW) pres[tid] = myPre;
    __syncthreads();

    // GEMV slice: each wave computes 2 rows' dot(W2_row, h).
    float acc0 = 0.f, acc1 = 0.f;
#pragma unroll
    for (int k = 0; k < DD / 256; ++k) {   // 8 iterations, dense conflict-free LDS
      const float4 hv = *(const float4*)&hs[k * 256 + 4 * lane];
      const float4 w0 = *(const float4*)&w2s[r0][k * 256 + 4 * lane];
      const float4 w1 = *(const float4*)&w2s[r1][k * 256 + 4 * lane];
      acc0 += w0.x * hv.x + w0.y * hv.y + w0.z * hv.z + w0.w * hv.w;
      acc1 += w1.x * hv.x + w1.y * hv.y + w1.z * hv.z + w1.w * hv.w;
    }
    acc0 = wave_sum(acc0);
    acc1 = wave_sum(acc1);

    if (lane == 0) {
      const float v0 = fmaxf(pres[r0] + b2r0 + acc0, 0.f);
      const float v1 = fmaxf(pres[r1] + b2r1 + acc1, 0.f);
      float* hb = hbuf + (size_t)((t + 1) & 1) * DD + wg * RPW;
      // Write-through (agent-scope) stores: land in LLC, visible cross-XCD.
      __hip_atomic_store(&hb[r0], v0, __ATOMIC_RELAXED, __HIP_MEMORY_SCOPE_AGENT);
      __hip_atomic_store(&hb[r1], v1, __ATOMIC_RELAXED, __HIP_MEMORY_SCOPE_AGENT);
    }
    __syncthreads();   // drains all waves' vmcnt -> chunk globally visible
    if (tid == 0) {
      __hip_atomic_store(&done[wg], t + 1, __ATOMIC_RELEASE,
                         __HIP_MEMORY_SCOPE_AGENT);
    }
  }

  if (wg != 0) return;

  // WG 0: out = Wf @ h_T + bf.  h_T sits in hbuf[TT & 1] == hbuf[0].
  while (__hip_atomic_load(&done[tid], __ATOMIC_ACQUIRE,
                           __HIP_MEMORY_SCOPE_AGENT) < TT) {
    __builtin_amdgcn_s_sleep(2);
  }
  {
    const float4* hb4 = (const float4*)hbuf;
    ((float4*)hs)[2 * tid]     = hb4[2 * tid];
    ((float4*)hs)[2 * tid + 1] = hb4[2 * tid + 1];
  }
  __syncthreads();
  float acc = 0.f;
#pragma unroll
  for (int k = 0; k < DD / 256; ++k) {
    const float4 wv = *(const float4*)(Wf + (size_t)wave * DD + k * 256 + 4 * lane);
    const float4 hv = *(const float4*)&hs[k * 256 + 4 * lane];
    acc += wv.x * hv.x + wv.y * hv.y + wv.z * hv.z + wv.w * hv.w;
  }
  acc = wave_sum(acc);
  if (lane == 0) out[wave] = acc + bf[wave];
}

// ---------------- Launch ----------------------------------------------------
extern "C" void kernel_launch(void* const* d_in, const int* in_sizes, int n_in,
                              void* d_out, int out_size, void* d_ws, size_t ws_size,
                              hipStream_t stream) {
  const float* x  = (const float*)d_in[0];   // (1, TT, DD)
  const float* h0 = (const float*)d_in[1];   // (1, DD)
  const float* W1 = (const float*)d_in[2];   // (DD, DD)
  const float* b1 = (const float*)d_in[3];   // (DD,)
  const float* W2 = (const float*)d_in[4];   // (DD, DD)
  const float* b2 = (const float*)d_in[5];   // (DD,)
  const float* Wf = (const float*)d_in[6];   // (4, DD)
  const float* bf = (const float*)d_in[7];   // (4,)
  float* out = (float*)d_out;                // (1, 4)

  // Workspace layout: pre (64 MB) | hbuf (16 KB) | done (1 KB)
  float* pre  = (float*)d_ws;
  float* hbuf = pre + (size_t)TT * DD;
  int*   done = (int*)(hbuf + 2 * DD);

  hipMemsetAsync(done, 0, NWG * sizeof(int), stream);
  gemm_abt_bias<<<dim3((TT / BM) * (DD / BN)), dim3(NTH), 0, stream>>>(
      x, W1, b1, pre, TT, DD, DD);
  recurrent_kernel<<<dim3(NWG), dim3(NTH), 0, stream>>>(
      h0, W2, b2, pre, Wf, bf, out, hbuf, done);
}

// Round 2
// 28050.519 us; speedup vs baseline: 6.3488x; 6.3488x over previous
//
#include <hip/hip_runtime.h>

#define TT 8192
#define DD 2048
#define NWG 256
#define RPW (DD / NWG)   // 8 rows of h per workgroup
#define NTH 256

typedef unsigned long long u64;
#define SIGN2 0x8000000080000000ULL

// ---------------- Phase 1: pre = x @ W1^T + b1  (M=TT, N=DD, K=DD) ----------
#define BM 128
#define BN 128
#define BK 16

__global__ __launch_bounds__(NTH)
void gemm_abt_bias(const float* __restrict__ A, const float* __restrict__ B,
                   const float* __restrict__ bias, float* __restrict__ C,
                   int M, int N, int K) {
  __shared__ float As[BK][BM + 4];
  __shared__ float Bs[BK][BN + 4];
  const int ntile = N / BN;
  const int bn = blockIdx.x % ntile;
  const int bm = blockIdx.x / ntile;
  const int tid = (int)threadIdx.x;
  const int tx = tid & 15;
  const int ty = tid >> 4;

  float acc[8][8];
#pragma unroll
  for (int i = 0; i < 8; ++i)
#pragma unroll
    for (int j = 0; j < 8; ++j) acc[i][j] = 0.f;

  for (int kt = 0; kt < K; kt += BK) {
#pragma unroll
    for (int i = 0; i < 2; ++i) {
      int f = tid + i * 256;
      int row = f >> 2, c4 = f & 3;
      const float4 av = *(const float4*)(A + (size_t)(bm * BM + row) * K + kt + c4 * 4);
      As[c4 * 4 + 0][row] = av.x; As[c4 * 4 + 1][row] = av.y;
      As[c4 * 4 + 2][row] = av.z; As[c4 * 4 + 3][row] = av.w;
      const float4 bv = *(const float4*)(B + (size_t)(bn * BN + row) * K + kt + c4 * 4);
      Bs[c4 * 4 + 0][row] = bv.x; Bs[c4 * 4 + 1][row] = bv.y;
      Bs[c4 * 4 + 2][row] = bv.z; Bs[c4 * 4 + 3][row] = bv.w;
    }
    __syncthreads();
#pragma unroll
    for (int kk = 0; kk < BK; ++kk) {
      float a[8], b[8];
      *(float4*)&a[0] = *(const float4*)&As[kk][ty * 8];
      *(float4*)&a[4] = *(const float4*)&As[kk][ty * 8 + 4];
      *(float4*)&b[0] = *(const float4*)&Bs[kk][tx * 8];
      *(float4*)&b[4] = *(const float4*)&Bs[kk][tx * 8 + 4];
#pragma unroll
      for (int i = 0; i < 8; ++i)
#pragma unroll
        for (int j = 0; j < 8; ++j) acc[i][j] += a[i] * b[j];
    }
    __syncthreads();
  }

  const int col0 = bn * BN + tx * 8;
  const float4 bv0 = *(const float4*)(bias + col0);
  const float4 bv1 = *(const float4*)(bias + col0 + 4);
#pragma unroll
  for (int i = 0; i < 8; ++i) {
    float* crow = C + (size_t)(bm * BM + ty * 8 + i) * N + col0;
    float4 v0 = { acc[i][0] + bv0.x, acc[i][1] + bv0.y, acc[i][2] + bv0.z, acc[i][3] + bv0.w };
    float4 v1 = { acc[i][4] + bv1.x, acc[i][5] + bv1.y, acc[i][6] + bv1.z, acc[i][7] + bv1.w };
    *(float4*)(crow) = v0;
    *(float4*)(crow + 4) = v1;
  }
}

// ---------------- Phase 2: persistent recurrent kernel ----------------------
__device__ __forceinline__ float wave_sum(float v) {
#pragma unroll
  for (int off = 32; off > 0; off >>= 1) v += __shfl_down(v, off, 64);
  return v;
}

__device__ __forceinline__ u64 aload(const u64* p) {
  return __hip_atomic_load(p, __ATOMIC_RELAXED, __HIP_MEMORY_SCOPE_AGENT);
}
__device__ __forceinline__ void astore(u64* p, u64 v) {
  __hip_atomic_store(p, v, __ATOMIC_RELAXED, __HIP_MEMORY_SCOPE_AGENT);
}

// Sync design (all relaxed agent-scope atomics; NO acquire/release -> no
// buffer_inv / wbl2 cache-maintenance storms):
//  * h values are ReLU outputs (>= 0) -> sign bits are free tag space.
//    h_t lives in slot (t&1); successive tenants of a slot are 2 steps apart,
//    so tag = (t>>1)&1 alternates per tenant. Producer stores 2 floats as one
//    8B atomic with both sign bits = tag: readiness travels WITH the data.
//  * WG0 is the aggregator: it polls all 256 chunks' tags, stages h, then
//    publishes a single `epoch` word. WGs 1..255 poll ONLY epoch (one address
//    -> one coalesced line-request per wave per poll), then single-shot load
//    the chunks (fresh in LLC: WG0 observed them there before publishing).
//  * Anti-poison init: slot0 = 0x00 (tag 0; first tenant h_2 has tag 1),
//    slot1 = 0xAA (tag 1; first tenant h_1 has tag 0), epoch = 0.
__global__ void __launch_bounds__(NTH, 1)
recurrent_kernel(const float* __restrict__ h0,
                 const float* __restrict__ W2,
                 const float* __restrict__ b2,
                 const float* __restrict__ pre,
                 const float* __restrict__ Wf,
                 const float* __restrict__ bf,
                 float* __restrict__ out,
                 float* hbuf,      // 2*DD floats, double-buffered h
                 int*   epoch) {   // 1 int
  __shared__ float w2s[RPW][DD];   // 64 KB: this WG's 8 rows of W2, pinned
  __shared__ float hs[DD];         // 8 KB: current h
  __shared__ float pres[RPW];

  const int wg   = (int)blockIdx.x;
  const int tid  = (int)threadIdx.x;
  const int lane = tid & 63;
  const int wave = tid >> 6;
  const int r0 = 2 * wave, r1 = 2 * wave + 1;

  {
    const float4* src = (const float4*)(W2 + (size_t)wg * RPW * DD);
    float4* dst = (float4*)&w2s[0][0];
    for (int i = tid; i < RPW * DD / 4; i += NTH) dst[i] = src[i];
  }
  const float b2r0 = b2[wg * RPW + r0];
  const float b2r1 = b2[wg * RPW + r1];

  u64* const hb0 = (u64*)hbuf;            // slot 0
  u64* const hb1 = (u64*)(hbuf + DD);     // slot 1

  for (int t = 0; t < TT; ++t) {
    float myPre = 0.f;
    if (tid < RPW) myPre = pre[(size_t)t * DD + wg * RPW + tid];

    if (t == 0) {
      ((float4*)hs)[2 * tid]     = ((const float4*)h0)[2 * tid];
      ((float4*)hs)[2 * tid + 1] = ((const float4*)h0)[2 * tid + 1];
    } else {
      u64* src = ((t & 1) ? hb1 : hb0) + 4 * tid;
      u64 u0, u1, u2, u3;
      if (wg == 0) {
        // Aggregator: thread tid polls chunk tid's 4 tagged ulongs.
        const u64 EXP = ((t >> 1) & 1) ? SIGN2 : 0ULL;
        for (;;) {
          u0 = aload(src + 0); u1 = aload(src + 1);
          u2 = aload(src + 2); u3 = aload(src + 3);
          if (((((u0 ^ EXP) | (u1 ^ EXP)) | ((u2 ^ EXP) | (u3 ^ EXP))) & SIGN2) == 0ULL)
            break;
          __builtin_amdgcn_s_sleep(1);
        }
      } else {
        // Consumers: poll the single epoch word (same-address -> coalesced).
        while (__hip_atomic_load(epoch, __ATOMIC_RELAXED, __HIP_MEMORY_SCOPE_AGENT) < t)
          __builtin_amdgcn_s_sleep(1);
        u0 = aload(src + 0); u1 = aload(src + 1);
        u2 = aload(src + 2); u3 = aload(src + 3);
      }
      u64* dst = (u64*)hs + 4 * tid;
      dst[0] = u0 & ~SIGN2; dst[1] = u1 & ~SIGN2;
      dst[2] = u2 & ~SIGN2; dst[3] = u3 & ~SIGN2;
    }
    if (tid < RPW) pres[tid] = myPre;
    __syncthreads();

    // WG0 publishes epoch t (all its threads verified all chunks of h_t).
    if (wg == 0 && tid == 0 && t >= 1) {
      __hip_atomic_store(epoch, t, __ATOMIC_RELAXED, __HIP_MEMORY_SCOPE_AGENT);
    }

    // GEMV slice: wave computes rows r0, r1.
    float acc0 = 0.f, acc1 = 0.f;
#pragma unroll
    for (int k = 0; k < DD / 256; ++k) {
      const float4 hv = *(const float4*)&hs[k * 256 + 4 * lane];
      const float4 w0 = *(const float4*)&w2s[r0][k * 256 + 4 * lane];
      const float4 w1 = *(const float4*)&w2s[r1][k * 256 + 4 * lane];
      acc0 += w0.x * hv.x + w0.y * hv.y + w0.z * hv.z + w0.w * hv.w;
      acc1 += w1.x * hv.x + w1.y * hv.y + w1.z * hv.z + w1.w * hv.w;
    }
    acc0 = wave_sum(acc0);
    acc1 = wave_sum(acc1);

    if (lane == 0) {
      const float v0 = fmaxf(pres[r0] + b2r0 + acc0, 0.f);
      const float v1 = fmaxf(pres[r1] + b2r1 + acc1, 0.f);
      u64 u = ((u64)__float_as_uint(v1) << 32) | (u64)__float_as_uint(v0);
      if (((t + 1) >> 1) & 1) u |= SIGN2;   // tag for this slot-tenancy
      astore((((t + 1) & 1) ? hb1 : hb0) + (wg * 4 + wave), u);
    }
    __syncthreads();   // protects hs reuse next iteration
  }

  if (wg != 0) return;

  // WG0: final out = Wf @ h_T + bf. h_8192: slot 0, tag (8192>>1)&1 = 0.
  {
    u64* src = hb0 + 4 * tid;
    const u64 EXP = 0ULL;
    u64 u0, u1, u2, u3;
    for (;;) {
      u0 = aload(src + 0); u1 = aload(src + 1);
      u2 = aload(src + 2); u3 = aload(src + 3);
      if (((((u0 ^ EXP) | (u1 ^ EXP)) | ((u2 ^ EXP) | (u3 ^ EXP))) & SIGN2) == 0ULL)
        break;
      __builtin_amdgcn_s_sleep(1);
    }
    u64* dst = (u64*)hs + 4 * tid;
    dst[0] = u0 & ~SIGN2; dst[1] = u1 & ~SIGN2;
    dst[2] = u2 & ~SIGN2; dst[3] = u3 & ~SIGN2;
  }
  __syncthreads();
  float acc = 0.f;
#pragma unroll
  for (int k = 0; k < DD / 256; ++k) {
    const float4 wv = *(const float4*)(Wf + (size_t)wave * DD + k * 256 + 4 * lane);
    const float4 hv = *(const float4*)&hs[k * 256 + 4 * lane];
    acc += wv.x * hv.x + wv.y * hv.y + wv.z * hv.z + wv.w * hv.w;
  }
  acc = wave_sum(acc);
  if (lane == 0) out[wave] = acc + bf[wave];
}

// ---------------- Launch ----------------------------------------------------
extern "C" void kernel_launch(void* const* d_in, const int* in_sizes, int n_in,
                              void* d_out, int out_size, void* d_ws, size_t ws_size,
                              hipStream_t stream) {
  const float* x  = (const float*)d_in[0];
  const float* h0 = (const float*)d_in[1];
  const float* W1 = (const float*)d_in[2];
  const float* b1 = (const float*)d_in[3];
  const float* W2 = (const float*)d_in[4];
  const float* b2 = (const float*)d_in[5];
  const float* Wf = (const float*)d_in[6];
  const float* bf = (const float*)d_in[7];
  float* out = (float*)d_out;

  // Workspace: pre (64 MB) | hbuf (16 KB) | epoch (4 B)
  float* pre   = (float*)d_ws;
  float* hbuf  = pre + (size_t)TT * DD;
  int*   epoch = (int*)(hbuf + 2 * DD);

  // Anti-poison slot init (see kernel comment) + epoch = 0.
  hipMemsetAsync(hbuf, 0x00, DD * sizeof(float), stream);        // slot0: tag 0
  hipMemsetAsync(hbuf + DD, 0xAA, DD * sizeof(float), stream);   // slot1: tag 1
  hipMemsetAsync(epoch, 0, sizeof(int), stream);

  gemm_abt_bias<<<dim3((TT / BM) * (DD / BN)), dim3(NTH), 0, stream>>>(
      x, W1, b1, pre, TT, DD, DD);
  recurrent_kernel<<<dim3(NWG), dim3(NTH), 0, stream>>>(
      h0, W2, b2, pre, Wf, bf, out, hbuf, epoch);
}